// Round 13
// baseline (31.824 us; speedup 1.0000x reference)
//
#include <hip/hip_runtime.h>
#include <math.h>

#define BS 16
#define NQ 100
#define NPTS 25
#define VOC 96
#define NC 97              // VOC+1 classes incl. padding
#define MAXLEN 25
#define NGT 32
#define EDIM 300
#define NCOL 512           // BS*NGT
#define NDIM 50            // NPTS*2

// ---------------- workspace layout (floats) ----------------
#define WS_GRAM 0                       // 97*96 = 9312 (row 96 = zeros)
#define WS_LOGP (WS_GRAM + NC * VOC)    // 1600*96
#define WS_CC   (WS_LOGP + 1600 * VOC)  // 1600
#define WS_TGTT (WS_CC + 1600)          // 50*512
#define WS_STAT (WS_TGTT + NDIM * NCOL) // 512*97: [pair][0..95]=ts, [96]=neg_ent

// ================= gram: 96 blocks x 128 (R1 shape) =================
__global__ __launch_bounds__(128) void gram_kernel(const float* __restrict__ cen,
                                                   float* __restrict__ gram) {
    __shared__ float row[EDIM];
    __shared__ float red[128];
    int blk = blockIdx.x, tid = threadIdx.x;
    for (int k = tid; k < EDIM; k += 128) row[k] = cen[blk * EDIM + k];
    if (blk == 0 && tid < VOC) gram[VOC * VOC + tid] = 0.f;   // zero pad row
    __syncthreads();
    float e = 0.f;
    if (tid < VOC) {
        float a0 = 0.f, a1 = 0.f;
        const float* c = cen + (size_t)tid * EDIM;
        for (int k = 0; k < EDIM; k += 2) { a0 += row[k] * c[k]; a1 += row[k + 1] * c[k + 1]; }
        e = __expf((a0 + a1) * 0.05773502691896258f);   // 1/sqrt(300)
    }
    red[tid] = e;
    __syncthreads();
    for (int s = 64; s; s >>= 1) { if (tid < s) red[tid] += red[tid + s]; __syncthreads(); }
    if (tid < VOC) gram[blk * VOC + tid] = e / red[0];
}

// ================= pred: 1600 blocks x 128 (R1 shape, store-back normalize) ============
__global__ __launch_bounds__(128) void pred_kernel(
        const float* __restrict__ logits1,   // (1600,25,1)
        const float* __restrict__ tlogits,   // (1600,25,97)
        float* __restrict__ logp, float* __restrict__ cc) {
    __shared__ float sm[NPTS * NC];          // 2425
    int u = blockIdx.x, tid = threadIdx.x;
    int wave = tid >> 6, lane = tid & 63;
    const float* src = tlogits + (size_t)u * NPTS * NC;
    for (int i = tid; i < NPTS * NC; i += 128) sm[i] = src[i];   // coalesced stage
    __syncthreads();
    for (int p = wave; p < NPTS; p += 2) {
        float* r = sm + p * NC;
        float x0 = r[lane];
        float x1 = (lane < 33) ? r[64 + lane] : 0.f;
        float e0 = __expf(x0);
        float e1 = (lane < 33) ? __expf(x1) : 0.f;
        float s = e0 + e1;
#pragma unroll
        for (int o = 32; o; o >>= 1) s += __shfl_xor(s, o);
        float inv = 1.f / s;
        r[lane] = e0 * inv;                  // normalized prob back to LDS
        if (lane < 33) r[64 + lane] = e1 * inv;
    }
    __syncthreads();
    if (tid < VOC) {
        float acc = 0.f;
#pragma unroll
        for (int p = 0; p < NPTS; ++p) acc += sm[p * NC + tid];
        logp[(size_t)u * VOC + tid] = __logf(fmaxf(acc * 0.04f, 1e-6f));
    }
    if (wave == 1) {
        float sig = 0.f;
        if (lane < NPTS) { float x = logits1[u * NPTS + lane]; sig = 1.f / (1.f + __expf(-x)); }
#pragma unroll
        for (int o = 32; o; o >>= 1) sig += __shfl_xor(sig, o);
        if (lane == 0) {
            float prob = sig * 0.04f;
            float negc = 0.75f * prob * prob * (-__logf(1.f - prob + 1e-8f));
            float posc = 0.25f * (1.f - prob) * (1.f - prob) * (-__logf(prob + 1e-8f));
            cc[u] = posc - negc;
        }
    }
}

// ================= transpose: 100 blocks x 256 =================
__global__ __launch_bounds__(256) void tr_kernel(const float* __restrict__ tgt_pts,
                                                 float* __restrict__ tgtT) {
    int gidx = blockIdx.x * 256 + threadIdx.x;   // < 25600 exactly
    int k = gidx >> 9, j = gidx & 511;
    tgtT[gidx] = tgt_pts[(size_t)j * NDIM + k];
}

// ================= stats: 128 blocks x 256, 1 pair/wave (R11 proven) =================
__global__ __launch_bounds__(256) void stats_kernel(
        const int*   __restrict__ texts,     // (512,25)
        const float* __restrict__ gram,      // (97,96), row 96 zeros
        float* __restrict__ stat) {          // (512,97)
    __shared__ int s_tex[4 * MAXLEN];
    int blk = blockIdx.x, tid = threadIdx.x;
    int wave = tid >> 6, lane = tid & 63;
    if (tid < 4 * MAXLEN) s_tex[tid] = texts[blk * 4 * MAXLEN + tid];
    __syncthreads();

    int vv[MAXLEN];
#pragma unroll
    for (int l = 0; l < MAXLEN; ++l) vv[l] = s_tex[wave * MAXLEN + l];
    int len = 0;
#pragma unroll
    for (int l = 0; l < MAXLEN; ++l) len += (vv[l] != VOC);
    float a0 = 0.f, a1 = 0.f;
#pragma unroll
    for (int l0 = 0; l0 < MAXLEN; l0 += 5) {
        float b0[5], b1[5];
#pragma unroll
        for (int q = 0; q < 5; ++q) {                 // 10 loads in flight
            const float* gr = gram + vv[l0 + q] * VOC;   // row 96 = zeros
            b0[q] = gr[lane];
            b1[q] = (lane < 32) ? gr[64 + lane] : 0.f;
        }
#pragma unroll
        for (int q = 0; q < 5; ++q) { a0 += b0[q]; a1 += b1[q]; }
    }
    float dinv = 1.f / (float)(len > 0 ? len : 1);
    float t0 = fmaxf(a0 * dinv, 1e-6f);
    float t1 = (lane < 32) ? fmaxf(a1 * dinv, 1e-6f) : 0.f;
    float s = t0 + t1;
#pragma unroll
    for (int o = 32; o; o >>= 1) s += __shfl_xor(s, o);
    float inv = 1.f / s;
    float ts0 = t0 * inv, ts1 = t1 * inv;
    float c0 = ts0 * __logf(ts0);
    float c1 = (lane < 32) ? ts1 * __logf(ts1) : 0.f;
    float ent = c0 + c1;
#pragma unroll
    for (int o = 32; o; o >>= 1) ent += __shfl_xor(ent, o);
    float* dst = stat + (size_t)(blk * 4 + wave) * NC;
    dst[lane] = len ? ts0 : 0.f;
    if (lane < 32) dst[64 + lane] = len ? ts1 : 0.f;
    if (lane == 0) dst[VOC] = len ? ent : 100.f;
}

// ================= asm: 1600 blocks x 256 = (row-pair, col-half) (R12 proven) ==========
__global__ __launch_bounds__(256) void asm_kernel(
        const float* __restrict__ pred_pts,  // (1600,50)
        const float* __restrict__ tgtT,      // (50,512)
        const float* __restrict__ logp,      // (1600,96)
        const float* __restrict__ cc,        // (1600,)
        const float* __restrict__ stat,      // (512,97)
        float* __restrict__ out) {           // (1600,512)
    __shared__ float s_lp[2][VOC];
    __shared__ float s_pp[2][NDIM];
    __shared__ float s_ct[2][NGT];
    __shared__ float spart[256];
    __shared__ float s_cc[2];

    int blk = blockIdx.x, tid = threadIdx.x;
    int pairIdx = blk >> 1, half = blk & 1;
    int r0 = pairIdx * 2;
    int b = pairIdx / 50;                    // rows 2k,2k+1 share image b = r0/100
    int col0 = half << 8;                    // 0 or 256
    bool hasText = ((b >> 3) == half);       // image b's 32 cols live in this half?

    // ---- stage (tiny, coalesced)
    if (tid < 2 * NDIM) { int r = tid >= NDIM, k = tid - r * NDIM; s_pp[r][k] = pred_pts[(size_t)(r0 + r) * NDIM + k]; }
    if (tid < 2) s_cc[tid] = cc[r0 + tid];
    if (hasText && tid >= 64 && tid < 64 + 2 * VOC) {
        int t = tid - 64;
        int r = t >= VOC, c = t - r * VOC;
        s_lp[r][c] = logp[(size_t)(r0 + r) * VOC + c];
    }
    __syncthreads();

    // ---- KL (only in the matching half): 256 thr = 64 (row,g) x 4 sub-chunks of 24
    if (hasText) {
        {
            int pair = tid >> 2, sub = tid & 3;
            int row = pair >> 5, g = pair & 31;
            const float* L = s_lp[row] + sub * 24;
            const float* S = stat + (size_t)(b * NGT + g) * NC + sub * 24;   // L2-resident
            float d0 = 0.f, d1 = 0.f;
#pragma unroll
            for (int j = 0; j < 24; j += 2) { d0 += L[j] * S[j]; d1 += L[j + 1] * S[j + 1]; }
            spart[tid] = d0 + d1;
        }
        __syncthreads();
        if (tid < 2 * NGT) {
            int row = tid >> 5, g = tid & 31;
            float s = spart[tid * 4] + spart[tid * 4 + 1] + spart[tid * 4 + 2] + spart[tid * 4 + 3];
            s_ct[row][g] = fmaxf(stat[(size_t)(b * NGT + g) * NC + VOC] - s, 0.f);
        }
    }

    // ---- L1 sweep: 2 rows x 1 col/thread over this half
    float a0 = 0.f, a1 = 0.f;
#pragma unroll 10
    for (int k = 0; k < NDIM; ++k) {
        float tv = tgtT[(k << 9) + col0 + tid];
        a0 += fabsf(s_pp[0][k] - tv);
        a1 += fabsf(s_pp[1][k] - tv);
    }
    __syncthreads();                         // s_ct visible

    int gb = tid >> 5, g = tid & 31;
    float m = (hasText && gb == (b & 7)) ? 1.f : 0.f;
    float c0v = s_cc[0], c1v = s_cc[1];
    float t0 = m * (hasText ? s_ct[0][g] : 0.f);
    float t1 = m * (hasText ? s_ct[1][g] : 0.f);
    out[(size_t)r0 * NCOL + col0 + tid]       = c0v + a0 + t0;
    out[(size_t)(r0 + 1) * NCOL + col0 + tid] = c1v + a1 + t1;
}

extern "C" void kernel_launch(void* const* d_in, const int* in_sizes, int n_in,
                              void* d_out, int out_size, void* d_ws, size_t ws_size,
                              hipStream_t stream) {
    const float* pred_logits      = (const float*)d_in[0];
    const float* pred_ctrl_points = (const float*)d_in[1];
    const float* pred_text_logits = (const float*)d_in[2];
    const float* tgt_ctrl_points  = (const float*)d_in[3];
    const int*   target_texts     = (const int*)d_in[4];
    const float* centroids        = (const float*)d_in[5];
    float* out = (float*)d_out;
    float* ws  = (float*)d_ws;

    float* gram = ws + WS_GRAM;
    float* logp = ws + WS_LOGP;
    float* cc   = ws + WS_CC;
    float* tgtT = ws + WS_TGTT;
    float* stat = ws + WS_STAT;

    gram_kernel<<<VOC, 128, 0, stream>>>(centroids, gram);
    pred_kernel<<<1600, 128, 0, stream>>>(pred_logits, pred_text_logits, logp, cc);
    tr_kernel<<<100, 256, 0, stream>>>(tgt_ctrl_points, tgtT);
    stats_kernel<<<128, 256, 0, stream>>>(target_texts, gram, stat);
    asm_kernel<<<1600, 256, 0, stream>>>(pred_ctrl_points, tgtT, logp, cc, stat, out);
}

// Round 14
// 26.142 us; speedup vs baseline: 1.2174x; 1.2174x over previous
//
#include <hip/hip_runtime.h>
#include <math.h>

#define BS 16
#define NQ 100
#define NPTS 25
#define VOC 96
#define NC 97              // VOC+1 classes incl. padding
#define MAXLEN 25
#define NGT 32
#define EDIM 300
#define NCOL 512           // BS*NGT
#define NDIM 50            // NPTS*2

// ---------------- workspace layout (floats) ----------------
#define WS_GRAM 0                       // 97*96 = 9312 (row 96 = zeros)
#define WS_LOGP (WS_GRAM + NC * VOC)    // 1600*96
#define WS_CC   (WS_LOGP + 1600 * VOC)  // 1600
#define WS_TGTT (WS_CC + 1600)          // 50*512
#define WS_STAT (WS_TGTT + NDIM * NCOL) // 512*97: [pair][0..95]=ts, [96]=neg_ent

#define GRAM_BLKS VOC              // 96
#define PRED_BLKS 800              // 2 units per block (1 per wave)
#define TR_BLKS 200                // 200*128 = 25600
#define K1_BLKS (GRAM_BLKS + PRED_BLKS + TR_BLKS)

// ---- K1: gram | pred (1 wave = 1 unit, fully register-local) | transpose
__global__ __launch_bounds__(128) void k1_kernel(
        const float* __restrict__ logits1,   // (1600,25,1)
        const float* __restrict__ tlogits,   // (1600,25,97)
        const float* __restrict__ cen,       // (96,300)
        const float* __restrict__ tgt_pts,   // (512,50)
        float* __restrict__ gram, float* __restrict__ logp,
        float* __restrict__ cost_class, float* __restrict__ tgtT) {
    __shared__ float smem[448];              // gram role only
    int blk = blockIdx.x, tid = threadIdx.x;
    int wave = tid >> 6, lane = tid & 63;

    if (blk < GRAM_BLKS) {
        // ---- gram row v = blk
        float* row = smem;                   // 300
        float* red = smem + 320;             // 128
        for (int k = tid; k < EDIM; k += 128) row[k] = cen[blk * EDIM + k];
        if (blk == 0 && tid < VOC) gram[VOC * VOC + tid] = 0.f;   // zero pad row
        __syncthreads();
        float e = 0.f;
        if (tid < VOC) {
            float a0 = 0.f, a1 = 0.f;
            const float* c = cen + (size_t)tid * EDIM;
            for (int k = 0; k < EDIM; k += 2) { a0 += row[k] * c[k]; a1 += row[k + 1] * c[k + 1]; }
            e = __expf((a0 + a1) * 0.05773502691896258f);
        }
        red[tid] = e;
        __syncthreads();
        for (int s = 64; s; s >>= 1) { if (tid < s) red[tid] += red[tid + s]; __syncthreads(); }
        if (tid < VOC) gram[blk * VOC + tid] = e / red[0];
    } else if (blk < GRAM_BLKS + PRED_BLKS) {
        // ---- pred: unit u per wave; everything register-local, no LDS/barriers
        int u = (blk - GRAM_BLKS) * 2 + wave;
        const float* base = tlogits + (size_t)u * NPTS * NC;
        float e0[NPTS], e1[NPTS], s[NPTS];
#pragma unroll
        for (int p = 0; p < NPTS; ++p) {
            float x0 = base[p * NC + lane];                       // class lane
            float x1 = (lane < 33) ? base[p * NC + 64 + lane] : 0.f;  // class 64+lane (incl 96)
            e0[p] = __expf(x0);
            e1[p] = (lane < 33) ? __expf(x1) : 0.f;
            s[p] = e0[p] + e1[p];
        }
        // 25 independent 6-step xor chains, interleaved -> pipelined
#pragma unroll
        for (int st = 32; st; st >>= 1) {
#pragma unroll
            for (int p = 0; p < NPTS; ++p) s[p] += __shfl_xor(s[p], st);
        }
        float acc0 = 0.f, acc1 = 0.f;                // lane-local class means
#pragma unroll
        for (int p = 0; p < NPTS; ++p) {
            float rinv = 1.f / s[p];
            acc0 += e0[p] * rinv;
            acc1 += e1[p] * rinv;
        }
        logp[(size_t)u * VOC + lane] = __logf(fmaxf(acc0 * 0.04f, 1e-6f));      // classes 0..63
        if (lane < 32)
            logp[(size_t)u * VOC + 64 + lane] = __logf(fmaxf(acc1 * 0.04f, 1e-6f)); // 64..95
        // focal cost
        float sig = 0.f;
        if (lane < NPTS) { float x = logits1[u * NPTS + lane]; sig = 1.f / (1.f + __expf(-x)); }
#pragma unroll
        for (int o = 32; o; o >>= 1) sig += __shfl_xor(sig, o);
        if (lane == 0) {
            float prob = sig * 0.04f;
            float negc = 0.75f * prob * prob * (-__logf(1.f - prob + 1e-8f));
            float posc = 0.25f * (1.f - prob) * (1.f - prob) * (-__logf(prob + 1e-8f));
            cost_class[u] = posc - negc;
        }
    } else {
        // ---- transpose tgt points (512,50) -> (50,512)
        int g = (blk - GRAM_BLKS - PRED_BLKS) * 128 + tid;   // < 25600 exactly
        int k = g / NCOL;
        int j = g - k * NCOL;
        tgtT[g] = tgt_pts[(size_t)j * NDIM + k];
    }
}

// ================= stats: 128 blocks x 256, 1 pair/wave (frozen, R11/R12) =================
__global__ __launch_bounds__(256) void stats_kernel(
        const int*   __restrict__ texts,     // (512,25)
        const float* __restrict__ gram,      // (97,96), row 96 zeros
        float* __restrict__ stat) {          // (512,97)
    __shared__ int s_tex[4 * MAXLEN];
    int blk = blockIdx.x, tid = threadIdx.x;
    int wave = tid >> 6, lane = tid & 63;
    if (tid < 4 * MAXLEN) s_tex[tid] = texts[blk * 4 * MAXLEN + tid];
    __syncthreads();

    int vv[MAXLEN];
#pragma unroll
    for (int l = 0; l < MAXLEN; ++l) vv[l] = s_tex[wave * MAXLEN + l];
    int len = 0;
#pragma unroll
    for (int l = 0; l < MAXLEN; ++l) len += (vv[l] != VOC);
    float a0 = 0.f, a1 = 0.f;
#pragma unroll
    for (int l0 = 0; l0 < MAXLEN; l0 += 5) {
        float b0[5], b1[5];
#pragma unroll
        for (int q = 0; q < 5; ++q) {
            const float* gr = gram + vv[l0 + q] * VOC;   // row 96 = zeros
            b0[q] = gr[lane];
            b1[q] = (lane < 32) ? gr[64 + lane] : 0.f;
        }
#pragma unroll
        for (int q = 0; q < 5; ++q) { a0 += b0[q]; a1 += b1[q]; }
    }
    float dinv = 1.f / (float)(len > 0 ? len : 1);
    float t0 = fmaxf(a0 * dinv, 1e-6f);
    float t1 = (lane < 32) ? fmaxf(a1 * dinv, 1e-6f) : 0.f;
    float s = t0 + t1;
#pragma unroll
    for (int o = 32; o; o >>= 1) s += __shfl_xor(s, o);
    float inv = 1.f / s;
    float ts0 = t0 * inv, ts1 = t1 * inv;
    float c0 = ts0 * __logf(ts0);
    float c1 = (lane < 32) ? ts1 * __logf(ts1) : 0.f;
    float ent = c0 + c1;
#pragma unroll
    for (int o = 32; o; o >>= 1) ent += __shfl_xor(ent, o);
    float* dst = stat + (size_t)(blk * 4 + wave) * NC;
    dst[lane] = len ? ts0 : 0.f;
    if (lane < 32) dst[64 + lane] = len ? ts1 : 0.f;
    if (lane == 0) dst[VOC] = len ? ent : 100.f;
}

// ================= asm: 1600 blocks x 256 = (row-pair, col-half) (frozen, R12) ==========
__global__ __launch_bounds__(256) void asm_kernel(
        const float* __restrict__ pred_pts,  // (1600,50)
        const float* __restrict__ tgtT,      // (50,512)
        const float* __restrict__ logp,      // (1600,96)
        const float* __restrict__ cc,        // (1600,)
        const float* __restrict__ stat,      // (512,97)
        float* __restrict__ out) {           // (1600,512)
    __shared__ float s_lp[2][VOC];
    __shared__ float s_pp[2][NDIM];
    __shared__ float s_ct[2][NGT];
    __shared__ float spart[256];
    __shared__ float s_cc[2];

    int blk = blockIdx.x, tid = threadIdx.x;
    int pairIdx = blk >> 1, half = blk & 1;
    int r0 = pairIdx * 2;
    int b = pairIdx / 50;
    int col0 = half << 8;
    bool hasText = ((b >> 3) == half);

    if (tid < 2 * NDIM) { int r = tid >= NDIM, k = tid - r * NDIM; s_pp[r][k] = pred_pts[(size_t)(r0 + r) * NDIM + k]; }
    if (tid < 2) s_cc[tid] = cc[r0 + tid];
    if (hasText && tid >= 64 && tid < 64 + 2 * VOC) {
        int t = tid - 64;
        int r = t >= VOC, c = t - r * VOC;
        s_lp[r][c] = logp[(size_t)(r0 + r) * VOC + c];
    }
    __syncthreads();

    if (hasText) {
        {
            int pair = tid >> 2, sub = tid & 3;
            int row = pair >> 5, g = pair & 31;
            const float* L = s_lp[row] + sub * 24;
            const float* S = stat + (size_t)(b * NGT + g) * NC + sub * 24;
            float d0 = 0.f, d1 = 0.f;
#pragma unroll
            for (int j = 0; j < 24; j += 2) { d0 += L[j] * S[j]; d1 += L[j + 1] * S[j + 1]; }
            spart[tid] = d0 + d1;
        }
        __syncthreads();
        if (tid < 2 * NGT) {
            int row = tid >> 5, g = tid & 31;
            float s = spart[tid * 4] + spart[tid * 4 + 1] + spart[tid * 4 + 2] + spart[tid * 4 + 3];
            s_ct[row][g] = fmaxf(stat[(size_t)(b * NGT + g) * NC + VOC] - s, 0.f);
        }
    }

    float a0 = 0.f, a1 = 0.f;
#pragma unroll 10
    for (int k = 0; k < NDIM; ++k) {
        float tv = tgtT[(k << 9) + col0 + tid];
        a0 += fabsf(s_pp[0][k] - tv);
        a1 += fabsf(s_pp[1][k] - tv);
    }
    __syncthreads();

    int gb = tid >> 5, g = tid & 31;
    float m = (hasText && gb == (b & 7)) ? 1.f : 0.f;
    float c0v = s_cc[0], c1v = s_cc[1];
    float t0 = m * (hasText ? s_ct[0][g] : 0.f);
    float t1 = m * (hasText ? s_ct[1][g] : 0.f);
    out[(size_t)r0 * NCOL + col0 + tid]       = c0v + a0 + t0;
    out[(size_t)(r0 + 1) * NCOL + col0 + tid] = c1v + a1 + t1;
}

extern "C" void kernel_launch(void* const* d_in, const int* in_sizes, int n_in,
                              void* d_out, int out_size, void* d_ws, size_t ws_size,
                              hipStream_t stream) {
    const float* pred_logits      = (const float*)d_in[0];
    const float* pred_ctrl_points = (const float*)d_in[1];
    const float* pred_text_logits = (const float*)d_in[2];
    const float* tgt_ctrl_points  = (const float*)d_in[3];
    const int*   target_texts     = (const int*)d_in[4];
    const float* centroids        = (const float*)d_in[5];
    float* out = (float*)d_out;
    float* ws  = (float*)d_ws;

    float* gram = ws + WS_GRAM;
    float* logp = ws + WS_LOGP;
    float* cc   = ws + WS_CC;
    float* tgtT = ws + WS_TGTT;
    float* stat = ws + WS_STAT;

    k1_kernel<<<K1_BLKS, 128, 0, stream>>>(pred_logits, pred_text_logits, centroids,
                                           tgt_ctrl_points, gram, logp, cc, tgtT);
    stats_kernel<<<128, 256, 0, stream>>>(target_texts, gram, stat);
    asm_kernel<<<1600, 256, 0, stream>>>(pred_ctrl_points, tgtT, logp, cc, stat, out);
}